// Round 1
// baseline (5823.937 us; speedup 1.0000x reference)
//
#include <hip/hip_runtime.h>

#define NN 100000
#define NE 1600000

// ---------------------------------------------------------------------------
// Scatter-add: for each edge e, agg[dst[e]] += feat[src[e]]  (+ deg[dst] += 1)
// 32 lanes per edge, each lane handles 4 consecutive floats (float4 gather).
// ---------------------------------------------------------------------------
__global__ __launch_bounds__(256) void k_scatter(const float* __restrict__ feat,
                                                 const int* __restrict__ src_idx,
                                                 const int* __restrict__ dst_idx,
                                                 float* __restrict__ agg,
                                                 float* __restrict__ deg,
                                                 int add_deg)
{
    int gid = blockIdx.x * 256 + threadIdx.x;
    int e    = gid >> 5;
    if (e >= NE) return;
    int lane = gid & 31;
    int s = src_idx[e];
    int d = dst_idx[e];
    float4 v = *reinterpret_cast<const float4*>(feat + (size_t)s * 128 + lane * 4);
    float* a = agg + (size_t)d * 128 + lane * 4;
    atomicAdd(a + 0, v.x);
    atomicAdd(a + 1, v.y);
    atomicAdd(a + 2, v.z);
    atomicAdd(a + 3, v.w);
    if (add_deg && lane == 0) atomicAdd(deg + d, 1.0f);
}

// ---------------------------------------------------------------------------
// Fused SAGE layer: out = [relu]( (agg*invdeg) @ Wl + xin @ Wr + bias )
// K = 128 fixed. Block = 128 threads. Tile: ROWS rows x COLS cols.
// A-tiles staged transposed in LDS (padded stride), W streamed from global.
// Per-thread register tile: 4 rows x 8 cols.
// ---------------------------------------------------------------------------
template <int COLS, int ROWS, bool RELU>
__global__ __launch_bounds__(128) void k_layer(const float* __restrict__ agg,
                                               const float* __restrict__ deg,
                                               const float* __restrict__ xin,
                                               const float* __restrict__ Wl,
                                               const float* __restrict__ Wr,
                                               const float* __restrict__ bias,
                                               float* __restrict__ out)
{
    constexpr int K   = 128;
    constexpr int STR = ROWS + 4;          // padded LDS stride (multiple of 4 floats)
    constexpr int CG  = COLS / 8;          // column groups of 8

    __shared__ float mT[K][STR];           // mean, transposed: mT[k][r]
    __shared__ float xT[K][STR];           // x,    transposed
    __shared__ float invd[ROWS];

    const int tid = threadIdx.x;
    const int n0  = blockIdx.x * ROWS;

    for (int r = tid; r < ROWS; r += 128) {
        int n = n0 + r;
        float dg = (n < NN) ? deg[n] : 1.0f;
        invd[r] = 1.0f / fmaxf(dg, 1.0f);
    }
    __syncthreads();

    for (int idx = tid; idx < ROWS * K; idx += 128) {
        int r = idx >> 7;                  // K == 128
        int k = idx & 127;
        int n = n0 + r;
        float a = 0.0f, b = 0.0f;
        if (n < NN) {
            a = agg[(size_t)n * K + k] * invd[r];
            b = xin[(size_t)n * K + k];
        }
        mT[k][r] = a;
        xT[k][r] = b;
    }
    __syncthreads();

    const int c8 = (tid % CG) * 8;
    const int r4 = (tid / CG) * 4;

    float acc[4][8];
#pragma unroll
    for (int i = 0; i < 4; ++i)
#pragma unroll
        for (int j = 0; j < 8; ++j) acc[i][j] = 0.0f;

#pragma unroll 2
    for (int k = 0; k < K; ++k) {
        float4 am = *reinterpret_cast<const float4*>(&mT[k][r4]);
        float4 ax = *reinterpret_cast<const float4*>(&xT[k][r4]);
        float4 wl0 = *reinterpret_cast<const float4*>(Wl + (size_t)k * COLS + c8);
        float4 wl1 = *reinterpret_cast<const float4*>(Wl + (size_t)k * COLS + c8 + 4);
        float4 wr0 = *reinterpret_cast<const float4*>(Wr + (size_t)k * COLS + c8);
        float4 wr1 = *reinterpret_cast<const float4*>(Wr + (size_t)k * COLS + c8 + 4);

        float am_[4] = {am.x, am.y, am.z, am.w};
        float ax_[4] = {ax.x, ax.y, ax.z, ax.w};
        float wl_[8] = {wl0.x, wl0.y, wl0.z, wl0.w, wl1.x, wl1.y, wl1.z, wl1.w};
        float wr_[8] = {wr0.x, wr0.y, wr0.z, wr0.w, wr1.x, wr1.y, wr1.z, wr1.w};

#pragma unroll
        for (int i = 0; i < 4; ++i)
#pragma unroll
            for (int j = 0; j < 8; ++j)
                acc[i][j] += am_[i] * wl_[j] + ax_[i] * wr_[j];
    }

    float bs[8];
#pragma unroll
    for (int j = 0; j < 8; ++j) bs[j] = bias[c8 + j];

#pragma unroll
    for (int i = 0; i < 4; ++i) {
        int n = n0 + r4 + i;
        if (n < NN) {
            float4 o0, o1;
            o0.x = acc[i][0] + bs[0];
            o0.y = acc[i][1] + bs[1];
            o0.z = acc[i][2] + bs[2];
            o0.w = acc[i][3] + bs[3];
            o1.x = acc[i][4] + bs[4];
            o1.y = acc[i][5] + bs[5];
            o1.z = acc[i][6] + bs[6];
            o1.w = acc[i][7] + bs[7];
            if (RELU) {
                o0.x = fmaxf(o0.x, 0.f); o0.y = fmaxf(o0.y, 0.f);
                o0.z = fmaxf(o0.z, 0.f); o0.w = fmaxf(o0.w, 0.f);
                o1.x = fmaxf(o1.x, 0.f); o1.y = fmaxf(o1.y, 0.f);
                o1.z = fmaxf(o1.z, 0.f); o1.w = fmaxf(o1.w, 0.f);
            }
            *reinterpret_cast<float4*>(out + (size_t)n * COLS + c8)     = o0;
            *reinterpret_cast<float4*>(out + (size_t)n * COLS + c8 + 4) = o1;
        }
    }
}

extern "C" void kernel_launch(void* const* d_in, const int* in_sizes, int n_in,
                              void* d_out, int out_size, void* d_ws, size_t ws_size,
                              hipStream_t stream)
{
    const float* x   = (const float*)d_in[0];
    const int*   ei  = (const int*)d_in[1];   // [2, NE] int32 (harness converts int64)
    const float* W1l = (const float*)d_in[2];
    const float* W1r = (const float*)d_in[3];
    const float* b1  = (const float*)d_in[4];
    const float* W2l = (const float*)d_in[5];
    const float* W2r = (const float*)d_in[6];
    const float* b2  = (const float*)d_in[7];
    float* out = (float*)d_out;
    float* ws  = (float*)d_ws;

    const size_t padN = (NN + 127) & ~127;    // 100096
    float* deg = ws;                          // [NN]
    float* agg = ws + padN;                   // [NN*128]
    float* h   = agg + (size_t)NN * 128;      // [NN*128]

    const int* src = ei;
    const int* dst = ei + NE;

    const int scatter_grid = (NE * 32) / 256; // 200000

    // ---- layer 1 ----
    hipMemsetAsync(deg, 0, (padN + (size_t)NN * 128) * sizeof(float), stream);
    k_scatter<<<scatter_grid, 256, 0, stream>>>(x, src, dst, agg, deg, 1);
    k_layer<128, 32, true><<<(NN + 31) / 32, 128, 0, stream>>>(agg, deg, x, W1l, W1r, b1, h);

    // ---- layer 2 ----
    hipMemsetAsync(agg, 0, (size_t)NN * 128 * sizeof(float), stream);
    k_scatter<<<scatter_grid, 256, 0, stream>>>(h, src, dst, agg, deg, 0);
    k_layer<64, 64, false><<<(NN + 63) / 64, 128, 0, stream>>>(agg, deg, h, W2l, W2r, b2, out);
}

// Round 2
// 786.947 us; speedup vs baseline: 7.4007x; 7.4007x over previous
//
#include <hip/hip_runtime.h>

#define NN 100000
#define NE 1600000
#define SCAN_BLK 1024
#define NB ((NN + SCAN_BLK - 1) / SCAN_BLK)   // 98

// ---------------------------------------------------------------------------
// CSR build: histogram -> exclusive scan -> fill
// ---------------------------------------------------------------------------
__global__ __launch_bounds__(256) void k_hist(const int* __restrict__ dst,
                                              int* __restrict__ cnt)
{
    int e = blockIdx.x * 256 + threadIdx.x;
    if (e < NE) atomicAdd(&cnt[dst[e]], 1);
}

// per-block exclusive scan over 1024 counts; writes local-exclusive partials
// to rowptr and the block total to bsum.
__global__ __launch_bounds__(256) void k_scan_local(const int* __restrict__ cnt,
                                                    int* __restrict__ rowptr,
                                                    int* __restrict__ bsum)
{
    __shared__ int tmp[256];
    const int tid  = threadIdx.x;
    const int base = blockIdx.x * SCAN_BLK + tid * 4;
    int v[4];
    int sum = 0;
#pragma unroll
    for (int j = 0; j < 4; ++j) {
        int idx = base + j;
        v[j] = (idx < NN) ? cnt[idx] : 0;
        sum += v[j];
    }
    tmp[tid] = sum;
    __syncthreads();
    for (int off = 1; off < 256; off <<= 1) {
        int t = (tid >= off) ? tmp[tid - off] : 0;
        __syncthreads();
        tmp[tid] += t;
        __syncthreads();
    }
    int run = tmp[tid] - sum;   // exclusive offset for this thread
#pragma unroll
    for (int j = 0; j < 4; ++j) {
        int idx = base + j;
        if (idx < NN) rowptr[idx] = run;
        run += v[j];
    }
    if (tid == 255) bsum[blockIdx.x] = tmp[255];
}

__global__ __launch_bounds__(128) void k_scan_bsum(const int* __restrict__ bsum,
                                                   int* __restrict__ boff)
{
    __shared__ int tmp[128];
    const int tid = threadIdx.x;
    int v = (tid < NB) ? bsum[tid] : 0;
    tmp[tid] = v;
    __syncthreads();
    for (int off = 1; off < 128; off <<= 1) {
        int t = (tid >= off) ? tmp[tid - off] : 0;
        __syncthreads();
        tmp[tid] += t;
        __syncthreads();
    }
    if (tid < NB) boff[tid] = tmp[tid] - v;   // exclusive
}

__global__ __launch_bounds__(256) void k_scan_add(int* __restrict__ rowptr,
                                                  const int* __restrict__ boff,
                                                  int* __restrict__ cursor)
{
    int i = blockIdx.x * 256 + threadIdx.x;
    if (i < NN) {
        int r = rowptr[i] + boff[i >> 10];
        rowptr[i] = r;
        cursor[i] = r;
    }
    if (i == 0) rowptr[NN] = NE;
}

__global__ __launch_bounds__(256) void k_fill(const int* __restrict__ src,
                                              const int* __restrict__ dst,
                                              int* __restrict__ cursor,
                                              int* __restrict__ col)
{
    int e = blockIdx.x * 256 + threadIdx.x;
    if (e < NE) {
        int d   = dst[e];
        int pos = atomicAdd(&cursor[d], 1);
        col[pos] = src[e];
    }
}

// ---------------------------------------------------------------------------
// Gather-mean: mean[n] = (1/max(deg,1)) * sum_{s in N(n)} feat[s]
// 32 lanes per node (float4 each), 8 nodes per 256-thread block.
// ---------------------------------------------------------------------------
__global__ __launch_bounds__(256) void k_gather_mean(const float* __restrict__ feat,
                                                     const int* __restrict__ rowptr,
                                                     const int* __restrict__ col,
                                                     float* __restrict__ mean)
{
    const int tid  = threadIdx.x;
    const int n    = blockIdx.x * 8 + (tid >> 5);
    const int lane = tid & 31;
    if (n >= NN) return;
    const int beg = rowptr[n];
    const int end = rowptr[n + 1];
    float4 acc = make_float4(0.f, 0.f, 0.f, 0.f);
    for (int e = beg; e < end; ++e) {
        int s = col[e];
        float4 v = *reinterpret_cast<const float4*>(feat + (size_t)s * 128 + lane * 4);
        acc.x += v.x; acc.y += v.y; acc.z += v.z; acc.w += v.w;
    }
    float inv = 1.0f / (float)max(end - beg, 1);
    acc.x *= inv; acc.y *= inv; acc.z *= inv; acc.w *= inv;
    *reinterpret_cast<float4*>(mean + (size_t)n * 128 + lane * 4) = acc;
}

// ---------------------------------------------------------------------------
// Fused SAGE layer: out = [relu]( mean @ Wl + xin @ Wr + bias )
// K = 128 fixed. Block = 128 threads. Per-thread register tile 4x8.
// ---------------------------------------------------------------------------
template <int COLS, int ROWS, bool RELU>
__global__ __launch_bounds__(128) void k_layer(const float* __restrict__ mean,
                                               const float* __restrict__ xin,
                                               const float* __restrict__ Wl,
                                               const float* __restrict__ Wr,
                                               const float* __restrict__ bias,
                                               float* __restrict__ out)
{
    constexpr int K   = 128;
    constexpr int STR = ROWS + 4;
    constexpr int CG  = COLS / 8;

    __shared__ float mT[K][STR];
    __shared__ float xT[K][STR];

    const int tid = threadIdx.x;
    const int n0  = blockIdx.x * ROWS;

    for (int idx = tid; idx < ROWS * K; idx += 128) {
        int r = idx >> 7;
        int k = idx & 127;
        int n = n0 + r;
        float a = 0.0f, b = 0.0f;
        if (n < NN) {
            a = mean[(size_t)n * K + k];
            b = xin[(size_t)n * K + k];
        }
        mT[k][r] = a;
        xT[k][r] = b;
    }
    __syncthreads();

    const int c8 = (tid % CG) * 8;
    const int r4 = (tid / CG) * 4;

    float acc[4][8];
#pragma unroll
    for (int i = 0; i < 4; ++i)
#pragma unroll
        for (int j = 0; j < 8; ++j) acc[i][j] = 0.0f;

#pragma unroll 2
    for (int k = 0; k < K; ++k) {
        float4 am = *reinterpret_cast<const float4*>(&mT[k][r4]);
        float4 ax = *reinterpret_cast<const float4*>(&xT[k][r4]);
        float4 wl0 = *reinterpret_cast<const float4*>(Wl + (size_t)k * COLS + c8);
        float4 wl1 = *reinterpret_cast<const float4*>(Wl + (size_t)k * COLS + c8 + 4);
        float4 wr0 = *reinterpret_cast<const float4*>(Wr + (size_t)k * COLS + c8);
        float4 wr1 = *reinterpret_cast<const float4*>(Wr + (size_t)k * COLS + c8 + 4);

        float am_[4] = {am.x, am.y, am.z, am.w};
        float ax_[4] = {ax.x, ax.y, ax.z, ax.w};
        float wl_[8] = {wl0.x, wl0.y, wl0.z, wl0.w, wl1.x, wl1.y, wl1.z, wl1.w};
        float wr_[8] = {wr0.x, wr0.y, wr0.z, wr0.w, wr1.x, wr1.y, wr1.z, wr1.w};

#pragma unroll
        for (int i = 0; i < 4; ++i)
#pragma unroll
            for (int j = 0; j < 8; ++j)
                acc[i][j] += am_[i] * wl_[j] + ax_[i] * wr_[j];
    }

    float bs[8];
#pragma unroll
    for (int j = 0; j < 8; ++j) bs[j] = bias[c8 + j];

#pragma unroll
    for (int i = 0; i < 4; ++i) {
        int n = n0 + r4 + i;
        if (n < NN) {
            float4 o0, o1;
            o0.x = acc[i][0] + bs[0];
            o0.y = acc[i][1] + bs[1];
            o0.z = acc[i][2] + bs[2];
            o0.w = acc[i][3] + bs[3];
            o1.x = acc[i][4] + bs[4];
            o1.y = acc[i][5] + bs[5];
            o1.z = acc[i][6] + bs[6];
            o1.w = acc[i][7] + bs[7];
            if (RELU) {
                o0.x = fmaxf(o0.x, 0.f); o0.y = fmaxf(o0.y, 0.f);
                o0.z = fmaxf(o0.z, 0.f); o0.w = fmaxf(o0.w, 0.f);
                o1.x = fmaxf(o1.x, 0.f); o1.y = fmaxf(o1.y, 0.f);
                o1.z = fmaxf(o1.z, 0.f); o1.w = fmaxf(o1.w, 0.f);
            }
            *reinterpret_cast<float4*>(out + (size_t)n * COLS + c8)     = o0;
            *reinterpret_cast<float4*>(out + (size_t)n * COLS + c8 + 4) = o1;
        }
    }
}

extern "C" void kernel_launch(void* const* d_in, const int* in_sizes, int n_in,
                              void* d_out, int out_size, void* d_ws, size_t ws_size,
                              hipStream_t stream)
{
    const float* x   = (const float*)d_in[0];
    const int*   ei  = (const int*)d_in[1];   // [2, NE] int32
    const float* W1l = (const float*)d_in[2];
    const float* W1r = (const float*)d_in[3];
    const float* b1  = (const float*)d_in[4];
    const float* W2l = (const float*)d_in[5];
    const float* W2r = (const float*)d_in[6];
    const float* b2  = (const float*)d_in[7];
    float* out = (float*)d_out;

    const int* src = ei;
    const int* dst = ei + NE;

    // workspace layout
    int* rowptr = (int*)d_ws;                 // NN+1
    int* cursor = rowptr + NN + 1;            // NN  (also the histogram buffer)
    int* col    = cursor + NN;                // NE
    int* bsum   = col + NE;                   // 256
    int* boff   = bsum + 256;                 // 256
    uintptr_t p = (uintptr_t)(boff + 256);
    p = (p + 255) & ~(uintptr_t)255;
    float* mean = (float*)p;                  // NN*128
    float* h    = mean + (size_t)NN * 128;    // NN*128

    // ---- CSR build (once; shared by both layers) ----
    hipMemsetAsync(cursor, 0, NN * sizeof(int), stream);
    k_hist<<<(NE + 255) / 256, 256, 0, stream>>>(dst, cursor);
    k_scan_local<<<NB, 256, 0, stream>>>(cursor, rowptr, bsum);
    k_scan_bsum<<<1, 128, 0, stream>>>(bsum, boff);
    k_scan_add<<<(NN + 255) / 256, 256, 0, stream>>>(rowptr, boff, cursor);
    k_fill<<<(NE + 255) / 256, 256, 0, stream>>>(src, dst, cursor, col);

    // ---- layer 1 ----
    k_gather_mean<<<(NN + 7) / 8, 256, 0, stream>>>(x, rowptr, col, mean);
    k_layer<128, 32, true><<<(NN + 31) / 32, 128, 0, stream>>>(mean, x, W1l, W1r, b1, h);

    // ---- layer 2 ----
    k_gather_mean<<<(NN + 7) / 8, 256, 0, stream>>>(h, rowptr, col, mean);
    k_layer<64, 64, false><<<(NN + 63) / 64, 128, 0, stream>>>(mean, h, W2l, W2r, b2, out);
}

// Round 3
// 443.153 us; speedup vs baseline: 13.1420x; 1.7758x over previous
//
#include <hip/hip_runtime.h>

#define NN 100000
#define NE 1600000
#define SCAN_BLK 1024
#define NB ((NN + SCAN_BLK - 1) / SCAN_BLK)   // 98

typedef __attribute__((ext_vector_type(8))) short short8;
typedef __attribute__((ext_vector_type(4))) float f32x4;

__device__ __forceinline__ ushort f2bf(float f) {
    uint u = __float_as_uint(f);
    return (ushort)((u + 0x7FFFu + ((u >> 16) & 1u)) >> 16);   // RNE
}
__device__ __forceinline__ float bflo(uint u) { return __uint_as_float(u << 16); }
__device__ __forceinline__ float bfhi(uint u) { return __uint_as_float(u & 0xffff0000u); }
__device__ __forceinline__ uint packbf(float a, float b) {
    return (uint)f2bf(a) | ((uint)f2bf(b) << 16);
}

// ---------------------------------------------------------------------------
// CSR build: histogram -> exclusive scan -> fill
// ---------------------------------------------------------------------------
__global__ __launch_bounds__(256) void k_hist(const int* __restrict__ dst,
                                              int* __restrict__ cnt)
{
    int e = blockIdx.x * 256 + threadIdx.x;
    if (e < NE) atomicAdd(&cnt[dst[e]], 1);
}

__global__ __launch_bounds__(256) void k_scan_local(const int* __restrict__ cnt,
                                                    int* __restrict__ rowptr,
                                                    int* __restrict__ bsum)
{
    __shared__ int tmp[256];
    const int tid  = threadIdx.x;
    const int base = blockIdx.x * SCAN_BLK + tid * 4;
    int v[4];
    int sum = 0;
#pragma unroll
    for (int j = 0; j < 4; ++j) {
        int idx = base + j;
        v[j] = (idx < NN) ? cnt[idx] : 0;
        sum += v[j];
    }
    tmp[tid] = sum;
    __syncthreads();
    for (int off = 1; off < 256; off <<= 1) {
        int t = (tid >= off) ? tmp[tid - off] : 0;
        __syncthreads();
        tmp[tid] += t;
        __syncthreads();
    }
    int run = tmp[tid] - sum;
#pragma unroll
    for (int j = 0; j < 4; ++j) {
        int idx = base + j;
        if (idx < NN) rowptr[idx] = run;
        run += v[j];
    }
    if (tid == 255) bsum[blockIdx.x] = tmp[255];
}

__global__ __launch_bounds__(128) void k_scan_bsum(const int* __restrict__ bsum,
                                                   int* __restrict__ boff)
{
    __shared__ int tmp[128];
    const int tid = threadIdx.x;
    int v = (tid < NB) ? bsum[tid] : 0;
    tmp[tid] = v;
    __syncthreads();
    for (int off = 1; off < 128; off <<= 1) {
        int t = (tid >= off) ? tmp[tid - off] : 0;
        __syncthreads();
        tmp[tid] += t;
        __syncthreads();
    }
    if (tid < NB) boff[tid] = tmp[tid] - v;
}

__global__ __launch_bounds__(256) void k_scan_add(int* __restrict__ rowptr,
                                                  const int* __restrict__ boff,
                                                  int* __restrict__ cursor)
{
    int i = blockIdx.x * 256 + threadIdx.x;
    if (i < NN) {
        int r = rowptr[i] + boff[i >> 10];
        rowptr[i] = r;
        cursor[i] = r;
    }
    if (i == 0) rowptr[NN] = NE;
}

__global__ __launch_bounds__(256) void k_fill(const int* __restrict__ src,
                                              const int* __restrict__ dst,
                                              int* __restrict__ cursor,
                                              int* __restrict__ col)
{
    int e = blockIdx.x * 256 + threadIdx.x;
    if (e < NE) {
        int d   = dst[e];
        int pos = atomicAdd(&cursor[d], 1);
        col[pos] = src[e];
    }
}

// ---------------------------------------------------------------------------
// Weight prep: WbT1[256][128] = [W1_l | W1_r]^T in bf16 (row = out col, k contig)
//              WbT2[128][128] = [W2_l | W2_r]^T in bf16
// ---------------------------------------------------------------------------
__global__ __launch_bounds__(256) void k_castw(const float* __restrict__ W1l,
                                               const float* __restrict__ W1r,
                                               const float* __restrict__ W2l,
                                               const float* __restrict__ W2r,
                                               ushort* __restrict__ WbT1,
                                               ushort* __restrict__ WbT2)
{
    int i = blockIdx.x * 256 + threadIdx.x;
    if (i < 256 * 128) {
        int c = i >> 7, k = i & 127;
        float v = (c < 128) ? W1l[k * 128 + c] : W1r[k * 128 + (c - 128)];
        WbT1[i] = f2bf(v);
    } else if (i < 256 * 128 + 128 * 128) {
        int j = i - 256 * 128;
        int c = j >> 7, k = j & 127;
        float v = (c < 64) ? W2l[k * 64 + c] : W2r[k * 64 + (c - 64)];
        WbT2[j] = f2bf(v);
    }
}

// ---------------------------------------------------------------------------
// MFMA GEMM: out[N][outW] (sub-block of cols) = A[N][128] @ Bt^T, Bt[outW][128]
// bf16 inputs, fp32 accumulate. Block: 64 rows x 64 cols, 4 waves (2x2).
// Full K=128 staged in XOR-swizzled LDS (A and Bt both [64][128] bf16).
// AF32: A is fp32 (x), convert during staging. YPART: add bias. YF32: fp32 out.
// ---------------------------------------------------------------------------
template <bool AF32, bool YPART, bool YF32>
__global__ __launch_bounds__(256) void k_gemm(const void* __restrict__ Ap,
                                              const ushort* __restrict__ Bt,
                                              const float* __restrict__ bias,
                                              void* __restrict__ outp,
                                              int outW)
{
    __shared__ ushort As[64 * 128];
    __shared__ ushort Bs[64 * 128];

    const int tid = threadIdx.x;
    const int bm = blockIdx.x, bn = blockIdx.y;
    const int n0 = bn * 64;

    // stage: 1024 chunks of 8 bf16 (16 B) each for A and B
    for (int c = tid; c < 1024; c += 256) {
        int row  = c >> 4;
        int coff = (c & 15) * 8;                   // element offset in row
        int gr   = bm * 64 + row;
        short8 va;
        if (gr < NN) {
            if (AF32) {
                const float* A = (const float*)Ap;
                float4 f0 = *reinterpret_cast<const float4*>(A + (size_t)gr * 128 + coff);
                float4 f1 = *reinterpret_cast<const float4*>(A + (size_t)gr * 128 + coff + 4);
                va[0] = (short)f2bf(f0.x); va[1] = (short)f2bf(f0.y);
                va[2] = (short)f2bf(f0.z); va[3] = (short)f2bf(f0.w);
                va[4] = (short)f2bf(f1.x); va[5] = (short)f2bf(f1.y);
                va[6] = (short)f2bf(f1.z); va[7] = (short)f2bf(f1.w);
            } else {
                const ushort* A = (const ushort*)Ap;
                va = *reinterpret_cast<const short8*>(A + (size_t)gr * 128 + coff);
            }
        } else {
            va = short8{0, 0, 0, 0, 0, 0, 0, 0};
        }
        int byte = row * 256 + coff * 2;
        byte ^= ((row & 7) << 4);                  // T2 swizzle
        *reinterpret_cast<short8*>(reinterpret_cast<char*>(As) + byte) = va;

        short8 vb = *reinterpret_cast<const short8*>(Bt + (size_t)(n0 + row) * 128 + coff);
        *reinterpret_cast<short8*>(reinterpret_cast<char*>(Bs) + byte) = vb;
    }
    __syncthreads();

    const int wid  = tid >> 6, lane = tid & 63;
    const int wm   = wid >> 1, wn = wid & 1;
    const int lr   = lane & 15;
    const int lk   = (lane >> 4) << 3;             // k offset 0/8/16/24

    f32x4 zero4 = {0.f, 0.f, 0.f, 0.f};
    f32x4 acc00 = zero4, acc01 = zero4, acc10 = zero4, acc11 = zero4;

    const char* pA = reinterpret_cast<const char*>(As);
    const char* pB = reinterpret_cast<const char*>(Bs);

#pragma unroll
    for (int ks = 0; ks < 4; ++ks) {
        int k2 = (ks * 32 + lk) * 2;               // byte offset of k within row
        int r;
        int byte;
        short8 a0, a1, b0, b1;
        r = wm * 32 + lr;       byte = r * 256 + k2; byte ^= ((r & 7) << 4);
        a0 = *reinterpret_cast<const short8*>(pA + byte);
        r = wm * 32 + 16 + lr;  byte = r * 256 + k2; byte ^= ((r & 7) << 4);
        a1 = *reinterpret_cast<const short8*>(pA + byte);
        r = wn * 32 + lr;       byte = r * 256 + k2; byte ^= ((r & 7) << 4);
        b0 = *reinterpret_cast<const short8*>(pB + byte);
        r = wn * 32 + 16 + lr;  byte = r * 256 + k2; byte ^= ((r & 7) << 4);
        b1 = *reinterpret_cast<const short8*>(pB + byte);

        acc00 = __builtin_amdgcn_mfma_f32_16x16x32_bf16(a0, b0, acc00, 0, 0, 0);
        acc01 = __builtin_amdgcn_mfma_f32_16x16x32_bf16(a0, b1, acc01, 0, 0, 0);
        acc10 = __builtin_amdgcn_mfma_f32_16x16x32_bf16(a1, b0, acc10, 0, 0, 0);
        acc11 = __builtin_amdgcn_mfma_f32_16x16x32_bf16(a1, b1, acc11, 0, 0, 0);
    }

    // epilogue: D mapping col = lane&15, row = 4*(lane>>4) + reg  [m89-verified]
#pragma unroll
    for (int mi = 0; mi < 2; ++mi) {
#pragma unroll
        for (int ni = 0; ni < 2; ++ni) {
            const f32x4 acc = (mi == 0) ? (ni == 0 ? acc00 : acc01)
                                        : (ni == 0 ? acc10 : acc11);
            int colg = bn * 64 + wn * 32 + ni * 16 + lr;
            float bv = YPART ? bias[colg] : 0.f;
#pragma unroll
            for (int rr = 0; rr < 4; ++rr) {
                int rowg = bm * 64 + wm * 32 + mi * 16 + ((lane >> 4) << 2) + rr;
                if (rowg < NN) {
                    float v = acc[rr] + bv;
                    if (YF32) ((float*)outp)[(size_t)rowg * outW + colg] = v;
                    else      ((ushort*)outp)[(size_t)rowg * outW + colg] = f2bf(v);
                }
            }
        }
    }
}

// ---------------------------------------------------------------------------
// Gather 1: hb[n] = relu( mean_{s in N(n)} z1b[s] + y1b[n] )   (128-wide bf16)
// One 64-lane wave per node; lane covers 2 elements (one uint).
// ---------------------------------------------------------------------------
__global__ __launch_bounds__(256) void k_gather1(const ushort* __restrict__ z1b,
                                                 const ushort* __restrict__ y1b,
                                                 const int* __restrict__ rowptr,
                                                 const int* __restrict__ col,
                                                 ushort* __restrict__ hb)
{
    const int w = threadIdx.x >> 6, lane = threadIdx.x & 63;
    const int n = blockIdx.x * 4 + w;
    if (n >= NN) return;
    const int beg = rowptr[n], end = rowptr[n + 1];
    float a0 = 0.f, a1 = 0.f;
    int e = beg;
    for (; e + 1 < end; e += 2) {
        int s0 = col[e], s1 = col[e + 1];
        uint u0 = *reinterpret_cast<const uint*>(z1b + (size_t)s0 * 128 + lane * 2);
        uint u1 = *reinterpret_cast<const uint*>(z1b + (size_t)s1 * 128 + lane * 2);
        a0 += bflo(u0) + bflo(u1);
        a1 += bfhi(u0) + bfhi(u1);
    }
    if (e < end) {
        int s0 = col[e];
        uint u0 = *reinterpret_cast<const uint*>(z1b + (size_t)s0 * 128 + lane * 2);
        a0 += bflo(u0);
        a1 += bfhi(u0);
    }
    float inv = 1.0f / (float)max(end - beg, 1);
    uint uy = *reinterpret_cast<const uint*>(y1b + (size_t)n * 128 + lane * 2);
    float h0 = fmaxf(a0 * inv + bflo(uy), 0.f);
    float h1 = fmaxf(a1 * inv + bfhi(uy), 0.f);
    *reinterpret_cast<uint*>(hb + (size_t)n * 128 + lane * 2) = packbf(h0, h1);
}

// ---------------------------------------------------------------------------
// Gather 2: out[n] = mean_{s in N(n)} z2b[s] + y2f[n]   (64-wide, fp32 out)
// 32-lane half-wave per node; lane covers 2 elements.
// ---------------------------------------------------------------------------
__global__ __launch_bounds__(256) void k_gather2(const ushort* __restrict__ z2b,
                                                 const float* __restrict__ y2f,
                                                 const int* __restrict__ rowptr,
                                                 const int* __restrict__ col,
                                                 float* __restrict__ out)
{
    const int g = threadIdx.x >> 5, lane = threadIdx.x & 31;
    const int n = blockIdx.x * 8 + g;
    if (n >= NN) return;
    const int beg = rowptr[n], end = rowptr[n + 1];
    float a0 = 0.f, a1 = 0.f;
    int e = beg;
    for (; e + 1 < end; e += 2) {
        int s0 = col[e], s1 = col[e + 1];
        uint u0 = *reinterpret_cast<const uint*>(z2b + (size_t)s0 * 64 + lane * 2);
        uint u1 = *reinterpret_cast<const uint*>(z2b + (size_t)s1 * 64 + lane * 2);
        a0 += bflo(u0) + bflo(u1);
        a1 += bfhi(u0) + bfhi(u1);
    }
    if (e < end) {
        int s0 = col[e];
        uint u0 = *reinterpret_cast<const uint*>(z2b + (size_t)s0 * 64 + lane * 2);
        a0 += bflo(u0);
        a1 += bfhi(u0);
    }
    float inv = 1.0f / (float)max(end - beg, 1);
    float2 y = *reinterpret_cast<const float2*>(y2f + (size_t)n * 64 + lane * 2);
    float2 o;
    o.x = a0 * inv + y.x;
    o.y = a1 * inv + y.y;
    *reinterpret_cast<float2*>(out + (size_t)n * 64 + lane * 2) = o;
}

extern "C" void kernel_launch(void* const* d_in, const int* in_sizes, int n_in,
                              void* d_out, int out_size, void* d_ws, size_t ws_size,
                              hipStream_t stream)
{
    const float* x   = (const float*)d_in[0];
    const int*   ei  = (const int*)d_in[1];
    const float* W1l = (const float*)d_in[2];
    const float* W1r = (const float*)d_in[3];
    const float* b1  = (const float*)d_in[4];
    const float* W2l = (const float*)d_in[5];
    const float* W2r = (const float*)d_in[6];
    const float* b2  = (const float*)d_in[7];
    float* out = (float*)d_out;

    const int* src = ei;
    const int* dst = ei + NE;

    // workspace layout
    int* rowptr = (int*)d_ws;                       // NN+1
    int* cursor = rowptr + NN + 1;                  // NN
    int* colA   = cursor + NN;                      // NE
    int* bsum   = colA + NE;                        // 256
    int* boff   = bsum + 256;                       // 256
    uintptr_t p = (uintptr_t)(boff + 256);
    p = (p + 255) & ~(uintptr_t)255;
    ushort* WbT1 = (ushort*)p;  p += (size_t)256 * 128 * 2;
    ushort* WbT2 = (ushort*)p;  p += (size_t)128 * 128 * 2;
    p = (p + 255) & ~(uintptr_t)255;
    ushort* z1b = (ushort*)p;   p += (size_t)NN * 128 * 2;
    ushort* y1b = (ushort*)p;   p += (size_t)NN * 128 * 2;
    ushort* hb  = (ushort*)p;   p += (size_t)NN * 128 * 2;
    // aliases (lifetimes disjoint): z2b over z1b, y2f over y1b
    ushort* z2b = z1b;                              // [NN][64] bf16
    float*  y2f = (float*)y1b;                      // [NN][64] fp32

    // ---- CSR build ----
    hipMemsetAsync(cursor, 0, NN * sizeof(int), stream);
    k_hist<<<(NE + 255) / 256, 256, 0, stream>>>(dst, cursor);
    k_scan_local<<<NB, 256, 0, stream>>>(cursor, rowptr, bsum);
    k_scan_bsum<<<1, 128, 0, stream>>>(bsum, boff);
    k_scan_add<<<(NN + 255) / 256, 256, 0, stream>>>(rowptr, boff, cursor);
    k_fill<<<(NE + 255) / 256, 256, 0, stream>>>(src, dst, cursor, colA);

    // ---- weights to bf16 (transposed) ----
    k_castw<<<(256 * 128 + 128 * 128 + 255) / 256, 256, 0, stream>>>(
        W1l, W1r, W2l, W2r, WbT1, WbT2);

    const int GM = (NN + 63) / 64;                  // 1563

    // ---- layer 1: z1 = x@W1l, y1 = x@W1r + b1 ----
    k_gemm<true, false, false><<<dim3(GM, 2), 256, 0, stream>>>(x, WbT1, nullptr, z1b, 128);
    k_gemm<true, true,  false><<<dim3(GM, 2), 256, 0, stream>>>(x, WbT1 + 128 * 128, b1, y1b, 128);
    k_gather1<<<(NN + 3) / 4, 256, 0, stream>>>(z1b, y1b, rowptr, colA, hb);

    // ---- layer 2: z2 = h@W2l, y2 = h@W2r + b2 ----
    k_gemm<false, false, false><<<dim3(GM, 1), 256, 0, stream>>>(hb, WbT2, nullptr, z2b, 64);
    k_gemm<false, true,  true ><<<dim3(GM, 1), 256, 0, stream>>>(hb, WbT2 + 64 * 128, b2, y2f, 64);
    k_gather2<<<(NN + 7) / 8, 256, 0, stream>>>(z2b, y2f, rowptr, colA, out);
}

// Round 4
// 311.632 us; speedup vs baseline: 18.6885x; 1.4220x over previous
//
#include <hip/hip_runtime.h>

#define NN 100000
#define NE 1600000
#define PSHIFT 9
#define PSZ 512
#define NP ((NN + PSZ - 1) / PSZ)             // 196
#define BCHUNK 8192
#define NBIN ((NE + BCHUNK - 1) / BCHUNK)     // 196
#define SRCMASK 0x1FFFF                       // 17 bits (NN < 131072)

typedef __attribute__((ext_vector_type(8))) short short8;
typedef __attribute__((ext_vector_type(4))) float f32x4;

__device__ __forceinline__ ushort f2bf(float f) {
    uint u = __float_as_uint(f);
    return (ushort)((u + 0x7FFFu + ((u >> 16) & 1u)) >> 16);   // RNE
}
__device__ __forceinline__ float bflo(uint u) { return __uint_as_float(u << 16); }
__device__ __forceinline__ float bfhi(uint u) { return __uint_as_float(u & 0xffff0000u); }
__device__ __forceinline__ uint packbf(float a, float b) {
    return (uint)f2bf(a) | ((uint)f2bf(b) << 16);
}

// ---------------------------------------------------------------------------
// CSR build, partition-local for write locality.
// ---------------------------------------------------------------------------
__global__ __launch_bounds__(256) void k_phist(const int* __restrict__ dst,
                                               int* __restrict__ pcnt)
{
    __shared__ int cnt[256];
    const int tid = threadIdx.x;
    cnt[tid] = 0;
    __syncthreads();
    const long e0 = (long)blockIdx.x * BCHUNK;
    for (int i = tid; i < BCHUNK; i += 256) {
        long e = e0 + i;
        if (e < NE) atomicAdd(&cnt[dst[e] >> PSHIFT], 1);
    }
    __syncthreads();
    if (cnt[tid] > 0) atomicAdd(&pcnt[tid], cnt[tid]);
}

__global__ __launch_bounds__(256) void k_pscan(const int* __restrict__ pcnt,
                                               int* __restrict__ poff,
                                               int* __restrict__ gcur,
                                               int* __restrict__ rowptr)
{
    __shared__ int tmp[256];
    const int tid = threadIdx.x;
    int v = (tid < NP) ? pcnt[tid] : 0;
    tmp[tid] = v;
    __syncthreads();
    for (int off = 1; off < 256; off <<= 1) {
        int t = (tid >= off) ? tmp[tid - off] : 0;
        __syncthreads();
        tmp[tid] += t;
        __syncthreads();
    }
    int ex = tmp[tid] - v;
    if (tid < NP) { poff[tid] = ex; gcur[tid] = ex; }
    if (tid == 0) { poff[NP] = NE; rowptr[NN] = NE; }
}

// bin edges by partition: packed[gpos] = src | (dlocal << 17)
__global__ __launch_bounds__(256) void k_binning(const int* __restrict__ src,
                                                 const int* __restrict__ dst,
                                                 int* __restrict__ gcur,
                                                 uint* __restrict__ packed)
{
    __shared__ int cnt[256];
    __shared__ int base[256];
    const int tid = threadIdx.x;
    const long e0 = (long)blockIdx.x * BCHUNK;
    cnt[tid] = 0;
    __syncthreads();
    for (int i = tid; i < BCHUNK; i += 256) {
        long e = e0 + i;
        if (e < NE) atomicAdd(&cnt[dst[e] >> PSHIFT], 1);
    }
    __syncthreads();
    if (cnt[tid] > 0) base[tid] = atomicAdd(&gcur[tid], cnt[tid]);
    cnt[tid] = 0;                       // reuse as run cursor
    __syncthreads();
    for (int i = tid; i < BCHUNK; i += 256) {
        long e = e0 + i;
        if (e < NE) {
            int d = dst[e], s = src[e];
            int p = d >> PSHIFT;
            int ofs = atomicAdd(&cnt[p], 1);
            packed[base[p] + ofs] = (uint)s | ((uint)(d & (PSZ - 1)) << 17);
        }
    }
}

// per-partition: count 512 local nodes, scan, write rowptr, place col
__global__ __launch_bounds__(256) void k_pfill(const uint* __restrict__ packed,
                                               const int* __restrict__ poff,
                                               int* __restrict__ rowptr,
                                               int* __restrict__ col)
{
    __shared__ int cnt[PSZ];
    __shared__ int cur[PSZ];
    __shared__ int tot[256];
    const int p   = blockIdx.x;
    const int tid = threadIdx.x;
    const int beg = poff[p], end = poff[p + 1];
    cnt[tid] = 0; cnt[tid + 256] = 0;
    __syncthreads();
    for (int i = beg + tid; i < end; i += 256)
        atomicAdd(&cnt[packed[i] >> 17], 1);
    __syncthreads();
    int v0 = cnt[tid * 2], v1 = cnt[tid * 2 + 1];
    int s  = v0 + v1;
    tot[tid] = s;
    __syncthreads();
    for (int off = 1; off < 256; off <<= 1) {
        int t = (tid >= off) ? tot[tid - off] : 0;
        __syncthreads();
        tot[tid] += t;
        __syncthreads();
    }
    int ex = tot[tid] - s + beg;
    cur[tid * 2]     = ex;
    cur[tid * 2 + 1] = ex + v0;
    int n0 = p * PSZ;
    if (n0 + tid * 2     < NN) rowptr[n0 + tid * 2]     = ex;
    if (n0 + tid * 2 + 1 < NN) rowptr[n0 + tid * 2 + 1] = ex + v0;
    __syncthreads();
    for (int i = beg + tid; i < end; i += 256) {
        uint v = packed[i];
        int pos = atomicAdd(&cur[v >> 17], 1);
        col[pos] = (int)(v & SRCMASK);
    }
}

// ---------------------------------------------------------------------------
// Weight prep: WbT1[256][128] = [W1_l | W1_r]^T bf16; WbT2[128][128]
// ---------------------------------------------------------------------------
__global__ __launch_bounds__(256) void k_castw(const float* __restrict__ W1l,
                                               const float* __restrict__ W1r,
                                               const float* __restrict__ W2l,
                                               const float* __restrict__ W2r,
                                               ushort* __restrict__ WbT1,
                                               ushort* __restrict__ WbT2)
{
    int i = blockIdx.x * 256 + threadIdx.x;
    if (i < 256 * 128) {
        int c = i >> 7, k = i & 127;
        float v = (c < 128) ? W1l[k * 128 + c] : W1r[k * 128 + (c - 128)];
        WbT1[i] = f2bf(v);
    } else if (i < 256 * 128 + 128 * 128) {
        int j = i - 256 * 128;
        int c = j >> 7, k = j & 127;
        float v = (c < 64) ? W2l[k * 64 + c] : W2r[k * 64 + (c - 64)];
        WbT2[j] = f2bf(v);
    }
}

// ---------------------------------------------------------------------------
// MFMA GEMM: 64x64 tile, 4 waves, full K=128 in XOR-swizzled LDS.
// ---------------------------------------------------------------------------
template <bool AF32, bool YPART, bool YF32>
__global__ __launch_bounds__(256) void k_gemm(const void* __restrict__ Ap,
                                              const ushort* __restrict__ Bt,
                                              const float* __restrict__ bias,
                                              void* __restrict__ outp,
                                              int outW)
{
    __shared__ ushort As[64 * 128];
    __shared__ ushort Bs[64 * 128];

    const int tid = threadIdx.x;
    const int bm = blockIdx.x, bn = blockIdx.y;
    const int n0 = bn * 64;

    for (int c = tid; c < 1024; c += 256) {
        int row  = c >> 4;
        int coff = (c & 15) * 8;
        int gr   = bm * 64 + row;
        short8 va;
        if (gr < NN) {
            if (AF32) {
                const float* A = (const float*)Ap;
                float4 f0 = *reinterpret_cast<const float4*>(A + (size_t)gr * 128 + coff);
                float4 f1 = *reinterpret_cast<const float4*>(A + (size_t)gr * 128 + coff + 4);
                va[0] = (short)f2bf(f0.x); va[1] = (short)f2bf(f0.y);
                va[2] = (short)f2bf(f0.z); va[3] = (short)f2bf(f0.w);
                va[4] = (short)f2bf(f1.x); va[5] = (short)f2bf(f1.y);
                va[6] = (short)f2bf(f1.z); va[7] = (short)f2bf(f1.w);
            } else {
                const ushort* A = (const ushort*)Ap;
                va = *reinterpret_cast<const short8*>(A + (size_t)gr * 128 + coff);
            }
        } else {
            va = short8{0, 0, 0, 0, 0, 0, 0, 0};
        }
        int byte = row * 256 + coff * 2;
        byte ^= ((row & 7) << 4);
        *reinterpret_cast<short8*>(reinterpret_cast<char*>(As) + byte) = va;

        short8 vb = *reinterpret_cast<const short8*>(Bt + (size_t)(n0 + row) * 128 + coff);
        *reinterpret_cast<short8*>(reinterpret_cast<char*>(Bs) + byte) = vb;
    }
    __syncthreads();

    const int wid  = tid >> 6, lane = tid & 63;
    const int wm   = wid >> 1, wn = wid & 1;
    const int lr   = lane & 15;
    const int lk   = (lane >> 4) << 3;

    f32x4 zero4 = {0.f, 0.f, 0.f, 0.f};
    f32x4 acc00 = zero4, acc01 = zero4, acc10 = zero4, acc11 = zero4;

    const char* pA = reinterpret_cast<const char*>(As);
    const char* pB = reinterpret_cast<const char*>(Bs);

#pragma unroll
    for (int ks = 0; ks < 4; ++ks) {
        int k2 = (ks * 32 + lk) * 2;
        int r, byte;
        short8 a0, a1, b0, b1;
        r = wm * 32 + lr;       byte = r * 256 + k2; byte ^= ((r & 7) << 4);
        a0 = *reinterpret_cast<const short8*>(pA + byte);
        r = wm * 32 + 16 + lr;  byte = r * 256 + k2; byte ^= ((r & 7) << 4);
        a1 = *reinterpret_cast<const short8*>(pA + byte);
        r = wn * 32 + lr;       byte = r * 256 + k2; byte ^= ((r & 7) << 4);
        b0 = *reinterpret_cast<const short8*>(pB + byte);
        r = wn * 32 + 16 + lr;  byte = r * 256 + k2; byte ^= ((r & 7) << 4);
        b1 = *reinterpret_cast<const short8*>(pB + byte);

        acc00 = __builtin_amdgcn_mfma_f32_16x16x32_bf16(a0, b0, acc00, 0, 0, 0);
        acc01 = __builtin_amdgcn_mfma_f32_16x16x32_bf16(a0, b1, acc01, 0, 0, 0);
        acc10 = __builtin_amdgcn_mfma_f32_16x16x32_bf16(a1, b0, acc10, 0, 0, 0);
        acc11 = __builtin_amdgcn_mfma_f32_16x16x32_bf16(a1, b1, acc11, 0, 0, 0);
    }

#pragma unroll
    for (int mi = 0; mi < 2; ++mi) {
#pragma unroll
        for (int ni = 0; ni < 2; ++ni) {
            const f32x4 acc = (mi == 0) ? (ni == 0 ? acc00 : acc01)
                                        : (ni == 0 ? acc10 : acc11);
            int colg = bn * 64 + wn * 32 + ni * 16 + lr;
            float bv = YPART ? bias[colg] : 0.f;
#pragma unroll
            for (int rr = 0; rr < 4; ++rr) {
                int rowg = bm * 64 + wm * 32 + mi * 16 + ((lane >> 4) << 2) + rr;
                if (rowg < NN) {
                    float v = acc[rr] + bv;
                    if (YF32) ((float*)outp)[(size_t)rowg * outW + colg] = v;
                    else      ((ushort*)outp)[(size_t)rowg * outW + colg] = f2bf(v);
                }
            }
        }
    }
}

// ---------------------------------------------------------------------------
// Gather 1: hb[n] = relu( mean z1b[nbrs] + y1b[n] )  (128-wide bf16)
// ---------------------------------------------------------------------------
__global__ __launch_bounds__(256) void k_gather1(const ushort* __restrict__ z1b,
                                                 const ushort* __restrict__ y1b,
                                                 const int* __restrict__ rowptr,
                                                 const int* __restrict__ col,
                                                 ushort* __restrict__ hb)
{
    const int w = threadIdx.x >> 6, lane = threadIdx.x & 63;
    const int n = blockIdx.x * 4 + w;
    if (n >= NN) return;
    const int beg = rowptr[n], end = rowptr[n + 1];
    float a0 = 0.f, a1 = 0.f;
    int e = beg;
    for (; e + 1 < end; e += 2) {
        int s0 = col[e], s1 = col[e + 1];
        uint u0 = *reinterpret_cast<const uint*>(z1b + (size_t)s0 * 128 + lane * 2);
        uint u1 = *reinterpret_cast<const uint*>(z1b + (size_t)s1 * 128 + lane * 2);
        a0 += bflo(u0) + bflo(u1);
        a1 += bfhi(u0) + bfhi(u1);
    }
    if (e < end) {
        int s0 = col[e];
        uint u0 = *reinterpret_cast<const uint*>(z1b + (size_t)s0 * 128 + lane * 2);
        a0 += bflo(u0);
        a1 += bfhi(u0);
    }
    float inv = 1.0f / (float)max(end - beg, 1);
    uint uy = *reinterpret_cast<const uint*>(y1b + (size_t)n * 128 + lane * 2);
    float h0 = fmaxf(a0 * inv + bflo(uy), 0.f);
    float h1 = fmaxf(a1 * inv + bfhi(uy), 0.f);
    *reinterpret_cast<uint*>(hb + (size_t)n * 128 + lane * 2) = packbf(h0, h1);
}

// ---------------------------------------------------------------------------
// Gather 2: out[n] = mean z2b[nbrs] + y2f[n]  (64-wide, fp32 out)
// ---------------------------------------------------------------------------
__global__ __launch_bounds__(256) void k_gather2(const ushort* __restrict__ z2b,
                                                 const float* __restrict__ y2f,
                                                 const int* __restrict__ rowptr,
                                                 const int* __restrict__ col,
                                                 float* __restrict__ out)
{
    const int g = threadIdx.x >> 5, lane = threadIdx.x & 31;
    const int n = blockIdx.x * 8 + g;
    if (n >= NN) return;
    const int beg = rowptr[n], end = rowptr[n + 1];
    float a0 = 0.f, a1 = 0.f;
    int e = beg;
    for (; e + 1 < end; e += 2) {
        int s0 = col[e], s1 = col[e + 1];
        uint u0 = *reinterpret_cast<const uint*>(z2b + (size_t)s0 * 64 + lane * 2);
        uint u1 = *reinterpret_cast<const uint*>(z2b + (size_t)s1 * 64 + lane * 2);
        a0 += bflo(u0) + bflo(u1);
        a1 += bfhi(u0) + bfhi(u1);
    }
    if (e < end) {
        int s0 = col[e];
        uint u0 = *reinterpret_cast<const uint*>(z2b + (size_t)s0 * 64 + lane * 2);
        a0 += bflo(u0);
        a1 += bfhi(u0);
    }
    float inv = 1.0f / (float)max(end - beg, 1);
    float2 y = *reinterpret_cast<const float2*>(y2f + (size_t)n * 64 + lane * 2);
    float2 o;
    o.x = a0 * inv + y.x;
    o.y = a1 * inv + y.y;
    *reinterpret_cast<float2*>(out + (size_t)n * 64 + lane * 2) = o;
}

extern "C" void kernel_launch(void* const* d_in, const int* in_sizes, int n_in,
                              void* d_out, int out_size, void* d_ws, size_t ws_size,
                              hipStream_t stream)
{
    const float* x   = (const float*)d_in[0];
    const int*   ei  = (const int*)d_in[1];
    const float* W1l = (const float*)d_in[2];
    const float* W1r = (const float*)d_in[3];
    const float* b1  = (const float*)d_in[4];
    const float* W2l = (const float*)d_in[5];
    const float* W2r = (const float*)d_in[6];
    const float* b2  = (const float*)d_in[7];
    float* out = (float*)d_out;

    const int* src = ei;
    const int* dst = ei + NE;

    // workspace layout
    int*  rowptr = (int*)d_ws;                      // NN+1
    int*  pcnt   = rowptr + NN + 1;                 // 256
    int*  poff   = pcnt + 256;                      // 256 (NP+1 used)
    int*  gcur   = poff + 256;                      // 256
    uint* packed = (uint*)(gcur + 256);             // NE
    int*  colA   = (int*)(packed + NE);             // NE
    uintptr_t p = (uintptr_t)(colA + NE);
    p = (p + 255) & ~(uintptr_t)255;
    ushort* WbT1 = (ushort*)p;  p += (size_t)256 * 128 * 2;
    ushort* WbT2 = (ushort*)p;  p += (size_t)128 * 128 * 2;
    p = (p + 255) & ~(uintptr_t)255;
    ushort* z1b = (ushort*)p;   p += (size_t)NN * 128 * 2;
    ushort* y1b = (ushort*)p;   p += (size_t)NN * 128 * 2;
    ushort* hb  = (ushort*)p;   p += (size_t)NN * 128 * 2;
    ushort* z2b = z1b;                              // aliases, disjoint lifetimes
    float*  y2f = (float*)y1b;

    // ---- CSR build (partition-local) ----
    hipMemsetAsync(pcnt, 0, 256 * sizeof(int), stream);
    k_phist<<<NBIN, 256, 0, stream>>>(dst, pcnt);
    k_pscan<<<1, 256, 0, stream>>>(pcnt, poff, gcur, rowptr);
    k_binning<<<NBIN, 256, 0, stream>>>(src, dst, gcur, packed);
    k_pfill<<<NP, 256, 0, stream>>>(packed, poff, rowptr, colA);

    // ---- weights to bf16 (transposed) ----
    k_castw<<<(256 * 128 + 128 * 128 + 255) / 256, 256, 0, stream>>>(
        W1l, W1r, W2l, W2r, WbT1, WbT2);

    const int GM = (NN + 63) / 64;                  // 1563

    // ---- layer 1: z1 = x@W1l, y1 = x@W1r + b1 ----
    k_gemm<true, false, false><<<dim3(GM, 2), 256, 0, stream>>>(x, WbT1, nullptr, z1b, 128);
    k_gemm<true, true,  false><<<dim3(GM, 2), 256, 0, stream>>>(x, WbT1 + 128 * 128, b1, y1b, 128);
    k_gather1<<<(NN + 3) / 4, 256, 0, stream>>>(z1b, y1b, rowptr, colA, hb);

    // ---- layer 2: z2 = h@W2l, y2 = h@W2r + b2 ----
    k_gemm<false, false, false><<<dim3(GM, 1), 256, 0, stream>>>(hb, WbT2, nullptr, z2b, 64);
    k_gemm<false, true,  true ><<<dim3(GM, 1), 256, 0, stream>>>(hb, WbT2 + 64 * 128, b2, y2f, 64);
    k_gather2<<<(NN + 7) / 8, 256, 0, stream>>>(z2b, y2f, rowptr, colA, out);
}